// Round 1
// baseline (742.793 us; speedup 1.0000x reference)
//
#include <hip/hip_runtime.h>
#include <cmath>

#define BSZ 8
#define TT  1024
#define EE  512
#define HH  8
#define CUc 6
#define HDD 64

typedef __bf16 bf16;
typedef __attribute__((ext_vector_type(4))) float f32x4;
typedef __attribute__((ext_vector_type(8))) float f32x8;
typedef __attribute__((ext_vector_type(8))) bf16  bf16x8;

static __device__ __forceinline__ f32x4 mfma16(bf16x8 a, bf16x8 b, f32x4 c) {
    return __builtin_amdgcn_mfma_f32_16x16x32_bf16(a, b, c, 0, 0, 0);
}

// ---------------------------------------------------------------- K1: projections
// Q = x @ wq^T etc. Split-bf16 (hi/lo) for Q,K; plain for V (stored transposed).
__global__ __launch_bounds__(256) void k_proj(
    const float* __restrict__ x,
    const float* __restrict__ wq, const float* __restrict__ wk, const float* __restrict__ wv,
    bf16* __restrict__ Qh, bf16* __restrict__ Ql,
    bf16* __restrict__ Kh, bf16* __restrict__ Kl,
    bf16* __restrict__ Vt)
{
    const int rb = blockIdx.x;          // 64-row block over BSZ*TT = 8192 rows
    const int cb = blockIdx.y;          // 64-col block over EE = 512 cols
    const int wid = threadIdx.x >> 6;
    const int l   = threadIdx.x & 63;
    const int lg = l >> 4, lr = l & 15;
    const int row = rb * 64 + wid * 16 + lr;   // A-frag row

    const float* W[3] = { wq, wk, wv };
    f32x4 acc[3][4];
#pragma unroll
    for (int m = 0; m < 3; ++m)
#pragma unroll
        for (int c = 0; c < 4; ++c) acc[m][c] = f32x4{0.f, 0.f, 0.f, 0.f};

    for (int ks = 0; ks < 16; ++ks) {
        const int e0 = ks * 32 + lg * 8;
        f32x8 xv = *(const f32x8*)(x + (size_t)row * EE + e0);
        bf16x8 xh, xl;
#pragma unroll
        for (int i = 0; i < 8; ++i) {
            bf16 h = (bf16)xv[i];
            xh[i] = h;
            xl[i] = (bf16)(xv[i] - (float)h);
        }
#pragma unroll
        for (int m = 0; m < 3; ++m) {
#pragma unroll
            for (int c = 0; c < 4; ++c) {
                const int f = cb * 64 + c * 16 + lr;
                f32x8 wvv = *(const f32x8*)(W[m] + (size_t)f * EE + e0);
                bf16x8 wh, wl;
#pragma unroll
                for (int i = 0; i < 8; ++i) {
                    bf16 h = (bf16)wvv[i];
                    wh[i] = h;
                    wl[i] = (bf16)(wvv[i] - (float)h);
                }
                acc[m][c] = mfma16(xh, wh, acc[m][c]);
                acc[m][c] = mfma16(xh, wl, acc[m][c]);
                acc[m][c] = mfma16(xl, wh, acc[m][c]);
            }
        }
    }

#pragma unroll
    for (int m = 0; m < 3; ++m)
#pragma unroll
        for (int c = 0; c < 4; ++c)
#pragma unroll
            for (int r = 0; r < 4; ++r) {
                const int orow = rb * 64 + wid * 16 + lg * 4 + r;   // C/D row map
                const int b = orow >> 10, t = orow & 1023;
                const int f = cb * 64 + c * 16 + lr;                // C/D col map
                const int h = f >> 6, d = f & 63;
                const float v = acc[m][c][r];
                if (m == 2) {
                    Vt[(((size_t)(b * HH + h) * HDD + d) * TT) + t] = (bf16)v;
                } else {
                    bf16 hi = (bf16)v;
                    bf16 lo = (bf16)(v - (float)hi);
                    const size_t idx = ((size_t)(b * HH + h) * TT + t) * HDD + d;
                    if (m == 0) { Qh[idx] = hi; Ql[idx] = lo; }
                    else        { Kh[idx] = hi; Kl[idx] = lo; }
                }
            }
}

// ---------------------------------------------------------------- K2: ubias -> attn region (f32, in place)
// ubias[b,h,i,j] = sum_c u[b,c,i,j]*wu[h,c] + bu[h];  -inf where umask[b,j,i,0]
__global__ __launch_bounds__(256) void k_ubias(
    const float* __restrict__ u, const unsigned char* __restrict__ umask,
    const float* __restrict__ wu, const float* __restrict__ bu,
    float* __restrict__ A)
{
    __shared__ __align__(16) unsigned char msk[64][64];   // [j-rel][i-rel]
    const int b  = blockIdx.z;
    const int i0 = blockIdx.y * 64;
    const int j0 = blockIdx.x * 64;
    const int t  = threadIdx.x;

    {   // stage mask tile, coalesced along i
        const int jj  = t >> 2;
        const int seg = (t & 3) * 16;
        *(uint4*)(&msk[jj][seg]) =
            *(const uint4*)(umask + ((size_t)b * TT + (j0 + jj)) * TT + i0 + seg);
    }
    float wuv[HH][CUc], buv[HH];
#pragma unroll
    for (int h = 0; h < HH; ++h) {
        buv[h] = bu[h];
#pragma unroll
        for (int c = 0; c < CUc; ++c) wuv[h][c] = wu[h * CUc + c];
    }
    __syncthreads();

    const int j = j0 + (t & 63);
    for (int ii = (t >> 6); ii < 64; ii += 4) {
        const int i = i0 + ii;
        float uv[CUc];
#pragma unroll
        for (int c = 0; c < CUc; ++c)
            uv[c] = u[(((size_t)b * CUc + c) * TT + i) * TT + j];
        const bool mk = msk[t & 63][ii] != 0;
#pragma unroll
        for (int h = 0; h < HH; ++h) {
            float v = buv[h];
#pragma unroll
            for (int c = 0; c < CUc; ++c) v += uv[c] * wuv[h][c];
            if (mk) v = -INFINITY;
            A[(((size_t)(b * HH + h) * TT + i) * TT) + j] = v;
        }
    }
}

// ---------------------------------------------------------------- K3: scores + softmax -> attn (f32)
// Two-pass per (b,h,16 q-rows per wave): pass1 online (m,s); pass2 recompute, write p.
__global__ __launch_bounds__(256) void k_attn(
    const bf16* __restrict__ Qh, const bf16* __restrict__ Ql,
    const bf16* __restrict__ Kh, const bf16* __restrict__ Kl,
    float* __restrict__ A)
{
    const int qb = blockIdx.x;     // 0..15 (64-row block)
    const int bh = blockIdx.y;     // 0..63
    const int wid = threadIdx.x >> 6;
    const int l = threadIdx.x & 63;
    const int lg = l >> 4, lr = l & 15;
    const int q0 = qb * 64 + wid * 16;

    const bf16* qbh = Qh + ((size_t)bh * TT + q0) * HDD;
    const bf16* qbl = Ql + ((size_t)bh * TT + q0) * HDD;
    bf16x8 qh0 = *(const bf16x8*)(qbh + lr * HDD + lg * 8);
    bf16x8 qh1 = *(const bf16x8*)(qbh + lr * HDD + 32 + lg * 8);
    bf16x8 ql0 = *(const bf16x8*)(qbl + lr * HDD + lg * 8);
    bf16x8 ql1 = *(const bf16x8*)(qbl + lr * HDD + 32 + lg * 8);

    const bf16* kbh = Kh + (size_t)bh * TT * HDD;
    const bf16* kbl = Kl + (size_t)bh * TT * HDD;
    float* Arow = A + ((size_t)bh * TT + q0) * TT;

    float m[4], s[4];
#pragma unroll
    for (int r = 0; r < 4; ++r) { m[r] = -INFINITY; s[r] = 0.f; }

    // ---- pass 1: per-lane online max/sum over this lane's columns
    for (int j0 = 0; j0 < TT; j0 += 16) {
        bf16x8 kh0 = *(const bf16x8*)(kbh + (size_t)(j0 + lr) * HDD + lg * 8);
        bf16x8 kh1 = *(const bf16x8*)(kbh + (size_t)(j0 + lr) * HDD + 32 + lg * 8);
        bf16x8 kl0 = *(const bf16x8*)(kbl + (size_t)(j0 + lr) * HDD + lg * 8);
        bf16x8 kl1 = *(const bf16x8*)(kbl + (size_t)(j0 + lr) * HDD + 32 + lg * 8);
        f32x4 acc = f32x4{0.f, 0.f, 0.f, 0.f};
        acc = mfma16(qh0, kh0, acc); acc = mfma16(qh1, kh1, acc);
        acc = mfma16(qh0, kl0, acc); acc = mfma16(qh1, kl1, acc);
        acc = mfma16(ql0, kh0, acc); acc = mfma16(ql1, kh1, acc);
#pragma unroll
        for (int r = 0; r < 4; ++r) {
            const float ub = Arow[(size_t)(lg * 4 + r) * TT + j0 + lr];
            const float v = acc[r] * 8.0f + ub;
            const float nm = fmaxf(m[r], v);
            s[r] = s[r] * __expf(m[r] - nm) + __expf(v - nm);
            m[r] = nm;
        }
    }
    // ---- merge (m,s) across the 16 lanes of each group
#pragma unroll
    for (int off = 1; off < 16; off <<= 1) {
#pragma unroll
        for (int r = 0; r < 4; ++r) {
            const float om = __shfl_xor(m[r], off);
            const float os = __shfl_xor(s[r], off);
            const float nm = fmaxf(m[r], om);
            s[r] = s[r] * __expf(m[r] - nm) + os * __expf(om - nm);
            m[r] = nm;
        }
    }
    float inv[4];
#pragma unroll
    for (int r = 0; r < 4; ++r) inv[r] = 1.0f / s[r];

    // ---- pass 2: recompute S, write normalized probabilities (overwrites ubias)
    for (int j0 = 0; j0 < TT; j0 += 16) {
        bf16x8 kh0 = *(const bf16x8*)(kbh + (size_t)(j0 + lr) * HDD + lg * 8);
        bf16x8 kh1 = *(const bf16x8*)(kbh + (size_t)(j0 + lr) * HDD + 32 + lg * 8);
        bf16x8 kl0 = *(const bf16x8*)(kbl + (size_t)(j0 + lr) * HDD + lg * 8);
        bf16x8 kl1 = *(const bf16x8*)(kbl + (size_t)(j0 + lr) * HDD + 32 + lg * 8);
        f32x4 acc = f32x4{0.f, 0.f, 0.f, 0.f};
        acc = mfma16(qh0, kh0, acc); acc = mfma16(qh1, kh1, acc);
        acc = mfma16(qh0, kl0, acc); acc = mfma16(qh1, kl1, acc);
        acc = mfma16(ql0, kh0, acc); acc = mfma16(ql1, kh1, acc);
#pragma unroll
        for (int r = 0; r < 4; ++r) {
            const size_t off = (size_t)(lg * 4 + r) * TT + j0 + lr;
            const float ub = Arow[off];
            const float v = acc[r] * 8.0f + ub;
            Arow[off] = __expf(v - m[r]) * inv[r];
        }
    }
}

// ---------------------------------------------------------------- K4: ctx = attn @ V  -> ctx bf16 [b,t,e]
__global__ __launch_bounds__(256) void k_ctx(
    const float* __restrict__ A, const bf16* __restrict__ Vt, bf16* __restrict__ ctx)
{
    const int qb = blockIdx.x;     // 0..15
    const int bh = blockIdx.y;     // 0..63
    const int wid = threadIdx.x >> 6;
    const int l = threadIdx.x & 63;
    const int lg = l >> 4, lr = l & 15;
    const int q0 = qb * 64 + wid * 16;

    const float* Ar = A + ((size_t)bh * TT + q0) * TT;
    const bf16* Vb = Vt + (size_t)bh * HDD * TT;

    f32x4 acc[4];
#pragma unroll
    for (int dt = 0; dt < 4; ++dt) acc[dt] = f32x4{0.f, 0.f, 0.f, 0.f};

    for (int k0 = 0; k0 < TT; k0 += 32) {
        f32x8 av = *(const f32x8*)(Ar + (size_t)lr * TT + k0 + lg * 8);
        bf16x8 af;
#pragma unroll
        for (int i = 0; i < 8; ++i) af[i] = (bf16)av[i];
#pragma unroll
        for (int dt = 0; dt < 4; ++dt) {
            bf16x8 bfv = *(const bf16x8*)(Vb + (size_t)(dt * 16 + lr) * TT + k0 + lg * 8);
            acc[dt] = mfma16(af, bfv, acc[dt]);
        }
    }
    const int b = bh >> 3, h = bh & 7;
#pragma unroll
    for (int dt = 0; dt < 4; ++dt)
#pragma unroll
        for (int r = 0; r < 4; ++r) {
            const int t = q0 + lg * 4 + r;
            ctx[((size_t)b * TT + t) * EE + h * HDD + dt * 16 + lr] = (bf16)acc[dt][r];
        }
}

// ---------------------------------------------------------------- K5: out = ctx @ wo^T + bo
__global__ __launch_bounds__(256) void k_out(
    const bf16* __restrict__ ctx, const float* __restrict__ wo,
    const float* __restrict__ bo, float* __restrict__ out)
{
    const int rb = blockIdx.x;
    const int cb = blockIdx.y;
    const int wid = threadIdx.x >> 6;
    const int l = threadIdx.x & 63;
    const int lg = l >> 4, lr = l & 15;
    const int row = rb * 64 + wid * 16 + lr;

    f32x4 acc[4];
#pragma unroll
    for (int c = 0; c < 4; ++c) acc[c] = f32x4{0.f, 0.f, 0.f, 0.f};

    for (int ks = 0; ks < 16; ++ks) {
        const int e0 = ks * 32 + lg * 8;
        bf16x8 af = *(const bf16x8*)(ctx + (size_t)row * EE + e0);
#pragma unroll
        for (int c = 0; c < 4; ++c) {
            const int f = cb * 64 + c * 16 + lr;
            f32x8 wvv = *(const f32x8*)(wo + (size_t)f * EE + e0);
            bf16x8 wf;
#pragma unroll
            for (int i = 0; i < 8; ++i) wf[i] = (bf16)wvv[i];
            acc[c] = mfma16(af, wf, acc[c]);
        }
    }
#pragma unroll
    for (int c = 0; c < 4; ++c) {
        const int f = cb * 64 + c * 16 + lr;
        const float bov = bo[f];
#pragma unroll
        for (int r = 0; r < 4; ++r) {
            const int orow = rb * 64 + wid * 16 + lg * 4 + r;
            out[(size_t)orow * EE + f] = acc[c][r] + bov;
        }
    }
}

// ----------------------------------------------------------------
extern "C" void kernel_launch(void* const* d_in, const int* in_sizes, int n_in,
                              void* d_out, int out_size, void* d_ws, size_t ws_size,
                              hipStream_t stream)
{
    (void)in_sizes; (void)n_in; (void)out_size; (void)ws_size;
    const float* x  = (const float*)d_in[0];
    const float* u  = (const float*)d_in[1];
    const unsigned char* umask = (const unsigned char*)d_in[2];
    const float* wq = (const float*)d_in[3];
    const float* wk = (const float*)d_in[4];
    const float* wv = (const float*)d_in[5];
    const float* wo = (const float*)d_in[6];
    const float* bo = (const float*)d_in[7];
    const float* wu = (const float*)d_in[8];
    const float* bu = (const float*)d_in[9];

    float* out = (float*)d_out;
    float* A   = out + (size_t)BSZ * TT * EE;     // attn region of d_out

    const size_t qs = (size_t)BSZ * HH * TT * HDD;  // 4,194,304 elems
    bf16* Qh = (bf16*)d_ws;
    bf16* Ql = Qh + qs;
    bf16* Kh = Ql + qs;
    bf16* Kl = Kh + qs;
    bf16* Vt = Kl + qs;
    bf16* ctx = Vt + qs;                            // total ws use: 50.3 MB

    k_proj <<<dim3(128, 8), 256, 0, stream>>>(x, wq, wk, wv, Qh, Ql, Kh, Kl, Vt);
    k_ubias<<<dim3(16, 16, 8), 256, 0, stream>>>(u, umask, wu, bu, A);
    k_attn <<<dim3(16, 64), 256, 0, stream>>>(Qh, Ql, Kh, Kl, A);
    k_ctx  <<<dim3(16, 64), 256, 0, stream>>>(A, Vt, ctx);
    k_out  <<<dim3(128, 8), 256, 0, stream>>>(ctx, wo, bo, out);
}

// Round 2
// 572.564 us; speedup vs baseline: 1.2973x; 1.2973x over previous
//
#include <hip/hip_runtime.h>
#include <cmath>

#define BSZ 8
#define TT  1024
#define EE  512
#define HH  8
#define CUc 6
#define HDD 64

typedef __bf16 bf16;
typedef __attribute__((ext_vector_type(4))) float f32x4;
typedef __attribute__((ext_vector_type(8))) float f32x8;
typedef __attribute__((ext_vector_type(8))) bf16  bf16x8;

static __device__ __forceinline__ f32x4 mfma16(bf16x8 a, bf16x8 b, f32x4 c) {
    return __builtin_amdgcn_mfma_f32_16x16x32_bf16(a, b, c, 0, 0, 0);
}

// ---------------------------------------------------------------- k_split: f32 -> hi (+lo) bf16
__global__ __launch_bounds__(256) void k_split(const float* __restrict__ src,
                                               bf16* __restrict__ hi, bf16* __restrict__ lo, int n)
{
    const int i = (blockIdx.x * 256 + threadIdx.x) * 8;
    if (i >= n) return;
    f32x8 v = *(const f32x8*)(src + i);
    bf16x8 h8, l8;
#pragma unroll
    for (int k = 0; k < 8; ++k) {
        bf16 h = (bf16)v[k];
        h8[k] = h;
        l8[k] = (bf16)(v[k] - (float)h);
    }
    *(bf16x8*)(hi + i) = h8;
    if (lo) *(bf16x8*)(lo + i) = l8;
}

// ---------------------------------------------------------------- k_proj2: x @ {wq,wk,wv}^T (pre-split weights)
__global__ __launch_bounds__(256) void k_proj2(
    const float* __restrict__ x,
    const bf16* __restrict__ wqh, const bf16* __restrict__ wql,
    const bf16* __restrict__ wkh, const bf16* __restrict__ wkl,
    const bf16* __restrict__ wvh,
    bf16* __restrict__ Qh, bf16* __restrict__ Ql,
    bf16* __restrict__ Kh, bf16* __restrict__ Kl,
    bf16* __restrict__ Vt)
{
    const int rb = blockIdx.x;          // 64-row block over 8192 rows
    const int cb = blockIdx.y;          // 64-col block over 512 cols
    const int wid = threadIdx.x >> 6;
    const int l   = threadIdx.x & 63;
    const int lg = l >> 4, lr = l & 15;
    const int row = rb * 64 + wid * 16 + lr;

    f32x4 aq[4], ak[4], av[4];
#pragma unroll
    for (int c = 0; c < 4; ++c) {
        aq[c] = f32x4{0.f,0.f,0.f,0.f}; ak[c] = f32x4{0.f,0.f,0.f,0.f}; av[c] = f32x4{0.f,0.f,0.f,0.f};
    }

    for (int ks = 0; ks < 16; ++ks) {
        const int e0 = ks * 32 + lg * 8;
        f32x8 xv = *(const f32x8*)(x + (size_t)row * EE + e0);
        bf16x8 xh, xl;
#pragma unroll
        for (int i = 0; i < 8; ++i) {
            bf16 h = (bf16)xv[i];
            xh[i] = h;
            xl[i] = (bf16)(xv[i] - (float)h);
        }
#pragma unroll
        for (int c = 0; c < 4; ++c) {
            const int f = cb * 64 + c * 16 + lr;
            const size_t wo = (size_t)f * EE + e0;
            bf16x8 qh = *(const bf16x8*)(wqh + wo);
            bf16x8 ql = *(const bf16x8*)(wql + wo);
            bf16x8 kh = *(const bf16x8*)(wkh + wo);
            bf16x8 kl = *(const bf16x8*)(wkl + wo);
            bf16x8 vh = *(const bf16x8*)(wvh + wo);
            aq[c] = mfma16(xh, qh, aq[c]); aq[c] = mfma16(xh, ql, aq[c]); aq[c] = mfma16(xl, qh, aq[c]);
            ak[c] = mfma16(xh, kh, ak[c]); ak[c] = mfma16(xh, kl, ak[c]); ak[c] = mfma16(xl, kh, ak[c]);
            av[c] = mfma16(xh, vh, av[c]);
        }
    }

#pragma unroll
    for (int c = 0; c < 4; ++c)
#pragma unroll
        for (int r = 0; r < 4; ++r) {
            const int orow = rb * 64 + wid * 16 + lg * 4 + r;
            const int b = orow >> 10, t = orow & 1023;
            const int f = cb * 64 + c * 16 + lr;
            const int h = f >> 6, d = f & 63;
            const size_t idx = ((size_t)(b * HH + h) * TT + t) * HDD + d;
            float vq = aq[c][r];
            bf16 qhi = (bf16)vq; Qh[idx] = qhi; Ql[idx] = (bf16)(vq - (float)qhi);
            float vk = ak[c][r];
            bf16 khi = (bf16)vk; Kh[idx] = khi; Kl[idx] = (bf16)(vk - (float)khi);
            Vt[(((size_t)(b * HH + h) * HDD + d) * TT) + t] = (bf16)av[c][r];
        }
}

// ---------------------------------------------------------------- k_ubias2: u -> bf16 ubias chunks inside attn region
// chunk(b,h,ib) = (bf16*)(A + ((bh*1024 + ib*16) * 1024)); layout [i&15][j]
__global__ __launch_bounds__(256) void k_ubias2(
    const float* __restrict__ u, const unsigned char* __restrict__ umask,
    const float* __restrict__ wu, const float* __restrict__ bu,
    float* __restrict__ A)
{
    __shared__ __align__(16) unsigned char msk[64][64];   // [j-rel][i-rel]
    const int b  = blockIdx.z;
    const int i0 = blockIdx.y * 64;
    const int j0 = blockIdx.x * 64;
    const int t  = threadIdx.x;

    {
        const int jj  = t >> 2;
        const int seg = (t & 3) * 16;
        *(uint4*)(&msk[jj][seg]) =
            *(const uint4*)(umask + ((size_t)b * TT + (j0 + jj)) * TT + i0 + seg);
    }
    float wuv[HH][CUc], buv[HH];
#pragma unroll
    for (int h = 0; h < HH; ++h) {
        buv[h] = bu[h];
#pragma unroll
        for (int c = 0; c < CUc; ++c) wuv[h][c] = wu[h * CUc + c];
    }
    __syncthreads();

    const int j = j0 + (t & 63);
    for (int ii = (t >> 6); ii < 64; ii += 4) {
        const int i = i0 + ii;
        float uv[CUc];
#pragma unroll
        for (int c = 0; c < CUc; ++c)
            uv[c] = u[(((size_t)b * CUc + c) * TT + i) * TT + j];
        const bool mk = msk[t & 63][ii] != 0;
#pragma unroll
        for (int h = 0; h < HH; ++h) {
            float v = buv[h];
#pragma unroll
            for (int c = 0; c < CUc; ++c) v += uv[c] * wuv[h][c];
            if (mk) v = -INFINITY;
            bf16* ub = (bf16*)(A + ((size_t)(b * HH + h) * TT + (i & ~15)) * TT);
            ub[(i & 15) * TT + j] = (bf16)v;
        }
    }
}

// ---------------------------------------------------------------- k_fused: scores + softmax + PV, heads serial
__global__ __launch_bounds__(512, 2) void k_fused(
    const bf16* __restrict__ Qh, const bf16* __restrict__ Ql,
    const bf16* __restrict__ Kh, const bf16* __restrict__ Kl,
    const bf16* __restrict__ Vt,
    float* __restrict__ A, bf16* __restrict__ ctx)
{
    const int b  = blockIdx.x & 7;          // batch per XCD (round-robin heuristic)
    const int ib = blockIdx.x >> 3;         // 0..63
    const int i0 = ib * 16;
    const int w  = threadIdx.x >> 6;        // 8 waves
    const int l  = threadIdx.x & 63;
    const int lg = l >> 4, lr = l & 15;
    const int jw = w * 128;                 // per-wave j-slice

    __shared__ __align__(16) bf16  P[16][1032];          // 33 KB (padded rows)
    __shared__ __align__(16) float ctxred[8][16][64];    // 32 KB
    __shared__ float mred[8][16], sred[8][16], sinv[16];

    for (int h = 0; h < HH; ++h) {
        const int bh = b * HH + h;

        // Q fragments (rows i0..i0+15)
        const bf16* qph = Qh + ((size_t)bh * TT + i0) * HDD;
        const bf16* qpl = Ql + ((size_t)bh * TT + i0) * HDD;
        bf16x8 qh0 = *(const bf16x8*)(qph + lr * HDD + lg * 8);
        bf16x8 qh1 = *(const bf16x8*)(qph + lr * HDD + 32 + lg * 8);
        bf16x8 ql0 = *(const bf16x8*)(qpl + lr * HDD + lg * 8);
        bf16x8 ql1 = *(const bf16x8*)(qpl + lr * HDD + 32 + lg * 8);

        const bf16* kph = Kh + (size_t)bh * TT * HDD;
        const bf16* kpl = Kl + (size_t)bh * TT * HDD;
        const bf16* ubc = (const bf16*)(A + ((size_t)bh * TT + i0) * TT);  // this block's UB chunk

        // ---- QK^T + ubias -> s (regs). lane holds rows lg*4+r, cols jw+jt*16+lr
        f32x4 s[8];
#pragma unroll
        for (int jt = 0; jt < 8; ++jt) {
            const int j = jw + jt * 16;
            bf16x8 kh0 = *(const bf16x8*)(kph + (size_t)(j + lr) * HDD + lg * 8);
            bf16x8 kh1 = *(const bf16x8*)(kph + (size_t)(j + lr) * HDD + 32 + lg * 8);
            bf16x8 kl0 = *(const bf16x8*)(kpl + (size_t)(j + lr) * HDD + lg * 8);
            bf16x8 kl1 = *(const bf16x8*)(kpl + (size_t)(j + lr) * HDD + 32 + lg * 8);
            f32x4 acc = f32x4{0.f,0.f,0.f,0.f};
            acc = mfma16(qh0, kh0, acc); acc = mfma16(qh1, kh1, acc);
            acc = mfma16(qh0, kl0, acc); acc = mfma16(qh1, kl1, acc);
            acc = mfma16(ql0, kh0, acc); acc = mfma16(ql1, kh1, acc);
#pragma unroll
            for (int r = 0; r < 4; ++r) {
                const float ub = (float)ubc[(size_t)(lg * 4 + r) * TT + j + lr];
                acc[r] = acc[r] * 8.0f + ub;
            }
            s[jt] = acc;
        }

        // ---- row max: local over jt, shuffle over 16 lanes, LDS across waves
        float m[4];
#pragma unroll
        for (int r = 0; r < 4; ++r) {
            float mm = s[0][r];
#pragma unroll
            for (int jt = 1; jt < 8; ++jt) mm = fmaxf(mm, s[jt][r]);
            m[r] = mm;
        }
#pragma unroll
        for (int off = 1; off < 16; off <<= 1)
#pragma unroll
            for (int r = 0; r < 4; ++r) m[r] = fmaxf(m[r], __shfl_xor(m[r], off));
        if (lr == 0)
#pragma unroll
            for (int r = 0; r < 4; ++r) mred[w][lg * 4 + r] = m[r];
        __syncthreads();                                   // B1
#pragma unroll
        for (int r = 0; r < 4; ++r) {
            float mm = mred[0][lg * 4 + r];
#pragma unroll
            for (int wv = 1; wv < 8; ++wv) mm = fmaxf(mm, mred[wv][lg * 4 + r]);
            m[r] = mm;
        }

        // ---- exp (unnormalized), P -> LDS bf16, row sums
        float sum[4] = {0.f, 0.f, 0.f, 0.f};
#pragma unroll
        for (int jt = 0; jt < 8; ++jt) {
#pragma unroll
            for (int r = 0; r < 4; ++r) {
                float p = __expf(s[jt][r] - m[r]);
                s[jt][r] = p;
                sum[r] += p;
                P[lg * 4 + r][jw + jt * 16 + lr] = (bf16)p;
            }
        }
#pragma unroll
        for (int off = 1; off < 16; off <<= 1)
#pragma unroll
            for (int r = 0; r < 4; ++r) sum[r] += __shfl_xor(sum[r], off);
        if (lr == 0)
#pragma unroll
            for (int r = 0; r < 4; ++r) sred[w][lg * 4 + r] = sum[r];
        __syncthreads();                                   // B2 (also publishes P)
        float inv[4];
#pragma unroll
        for (int r = 0; r < 4; ++r) {
            float ss = sred[0][lg * 4 + r];
#pragma unroll
            for (int wv = 1; wv < 8; ++wv) ss += sred[wv][lg * 4 + r];
            inv[r] = 1.0f / ss;
        }
        if (w == 0 && lr == 0)
#pragma unroll
            for (int r = 0; r < 4; ++r) sinv[lg * 4 + r] = inv[r];

        // ---- attn output (normalized, f32) — overwrites this block's UB chunk (reads done pre-B1)
        float* Ar = A + ((size_t)bh * TT + i0) * TT;
#pragma unroll
        for (int jt = 0; jt < 8; ++jt)
#pragma unroll
            for (int r = 0; r < 4; ++r)
                Ar[(size_t)(lg * 4 + r) * TT + jw + jt * 16 + lr] = s[jt][r] * inv[r];

        // ---- PV: per-wave k-slice [jw, jw+128)
        const bf16* vp = Vt + (size_t)bh * HDD * TT;
        f32x4 cacc[4];
#pragma unroll
        for (int dt = 0; dt < 4; ++dt) cacc[dt] = f32x4{0.f,0.f,0.f,0.f};
#pragma unroll
        for (int ks = 0; ks < 4; ++ks) {
            const int k0 = jw + ks * 32;
            bf16x8 a = *(const bf16x8*)(&P[lr][k0 + lg * 8]);
#pragma unroll
            for (int dt = 0; dt < 4; ++dt) {
                bf16x8 bv = *(const bf16x8*)(vp + (size_t)(dt * 16 + lr) * TT + k0 + lg * 8);
                cacc[dt] = mfma16(a, bv, cacc[dt]);
            }
        }
#pragma unroll
        for (int dt = 0; dt < 4; ++dt)
#pragma unroll
            for (int r = 0; r < 4; ++r)
                ctxred[w][lg * 4 + r][dt * 16 + lr] = cacc[dt][r];
        __syncthreads();                                   // B3

        // ---- reduce 8 partials, scale by 1/s, store ctx
        for (int o = threadIdx.x; o < 16 * 64; o += 512) {
            const int rr = o >> 6, d = o & 63;
            float sm = 0.f;
#pragma unroll
            for (int wv = 0; wv < 8; ++wv) sm += ctxred[wv][rr][d];
            ctx[((size_t)b * TT + i0 + rr) * EE + h * HDD + d] = (bf16)(sm * sinv[rr]);
        }
    }
}

// ---------------------------------------------------------------- k_out2: out = ctx @ wo^T + bo
__global__ __launch_bounds__(256) void k_out2(
    const bf16* __restrict__ ctx, const bf16* __restrict__ woh,
    const float* __restrict__ bo, float* __restrict__ out)
{
    const int rb = blockIdx.x;
    const int cb = blockIdx.y;
    const int wid = threadIdx.x >> 6;
    const int l = threadIdx.x & 63;
    const int lg = l >> 4, lr = l & 15;
    const int row = rb * 64 + wid * 16 + lr;

    f32x4 acc[4];
#pragma unroll
    for (int c = 0; c < 4; ++c) acc[c] = f32x4{0.f,0.f,0.f,0.f};

    for (int ks = 0; ks < 16; ++ks) {
        const int e0 = ks * 32 + lg * 8;
        bf16x8 af = *(const bf16x8*)(ctx + (size_t)row * EE + e0);
#pragma unroll
        for (int c = 0; c < 4; ++c) {
            const int f = cb * 64 + c * 16 + lr;
            bf16x8 wf = *(const bf16x8*)(woh + (size_t)f * EE + e0);
            acc[c] = mfma16(af, wf, acc[c]);
        }
    }
#pragma unroll
    for (int c = 0; c < 4; ++c) {
        const int f = cb * 64 + c * 16 + lr;
        const float bov = bo[f];
#pragma unroll
        for (int r = 0; r < 4; ++r) {
            const int orow = rb * 64 + wid * 16 + lg * 4 + r;
            out[(size_t)orow * EE + f] = acc[c][r] + bov;
        }
    }
}

// ----------------------------------------------------------------
extern "C" void kernel_launch(void* const* d_in, const int* in_sizes, int n_in,
                              void* d_out, int out_size, void* d_ws, size_t ws_size,
                              hipStream_t stream)
{
    (void)in_sizes; (void)n_in; (void)out_size; (void)ws_size;
    const float* x  = (const float*)d_in[0];
    const float* u  = (const float*)d_in[1];
    const unsigned char* umask = (const unsigned char*)d_in[2];
    const float* wq = (const float*)d_in[3];
    const float* wk = (const float*)d_in[4];
    const float* wv = (const float*)d_in[5];
    const float* wo = (const float*)d_in[6];
    const float* bo = (const float*)d_in[7];
    const float* wu = (const float*)d_in[8];
    const float* bu = (const float*)d_in[9];

    float* out = (float*)d_out;
    float* A   = out + (size_t)BSZ * TT * EE;       // attn region of d_out

    const size_t qs = (size_t)BSZ * HH * TT * HDD;  // 4,194,304
    const size_t wsz = (size_t)EE * EE;             // 262,144
    bf16* Qh  = (bf16*)d_ws;
    bf16* Ql  = Qh + qs;
    bf16* Kh  = Ql + qs;
    bf16* Kl  = Kh + qs;
    bf16* Vt  = Kl + qs;
    bf16* ctx = Vt + qs;
    bf16* wqh = ctx + qs;
    bf16* wql = wqh + wsz;
    bf16* wkh = wql + wsz;
    bf16* wkl = wkh + wsz;
    bf16* wvh = wkl + wsz;
    bf16* woh = wvh + wsz;                          // total ws: ~51.5 MB

    k_split<<<128, 256, 0, stream>>>(wq, wqh, wql, (int)wsz);
    k_split<<<128, 256, 0, stream>>>(wk, wkh, wkl, (int)wsz);
    k_split<<<128, 256, 0, stream>>>(wv, wvh, nullptr, (int)wsz);
    k_split<<<128, 256, 0, stream>>>(wo, woh, nullptr, (int)wsz);

    k_proj2 <<<dim3(128, 8), 256, 0, stream>>>(x, wqh, wql, wkh, wkl, wvh, Qh, Ql, Kh, Kl, Vt);
    k_ubias2<<<dim3(16, 16, 8), 256, 0, stream>>>(u, umask, wu, bu, A);
    k_fused <<<512, 512, 0, stream>>>(Qh, Ql, Kh, Kl, Vt, A, ctx);
    k_out2  <<<dim3(128, 8), 256, 0, stream>>>(ctx, woh, bo, out);
}

// Round 3
// 530.924 us; speedup vs baseline: 1.3991x; 1.0784x over previous
//
#include <hip/hip_runtime.h>
#include <cmath>

#define BSZ 8
#define TT  1024
#define EE  512
#define HH  8
#define CUc 6
#define HDD 64

typedef __bf16 bf16;
typedef __attribute__((ext_vector_type(4))) float f32x4;
typedef __attribute__((ext_vector_type(8))) float f32x8;
typedef __attribute__((ext_vector_type(8))) bf16  bf16x8;

static __device__ __forceinline__ f32x4 mfma16(bf16x8 a, bf16x8 b, f32x4 c) {
    return __builtin_amdgcn_mfma_f32_16x16x32_bf16(a, b, c, 0, 0, 0);
}

// ---------------------------------------------------------------- k_split: f32 -> hi (+lo) bf16
__global__ __launch_bounds__(256) void k_split(const float* __restrict__ src,
                                               bf16* __restrict__ hi, bf16* __restrict__ lo, int n)
{
    const int i = (blockIdx.x * 256 + threadIdx.x) * 8;
    if (i >= n) return;
    f32x8 v = *(const f32x8*)(src + i);
    bf16x8 h8, l8;
#pragma unroll
    for (int k = 0; k < 8; ++k) {
        bf16 h = (bf16)v[k];
        h8[k] = h;
        l8[k] = (bf16)(v[k] - (float)h);
    }
    *(bf16x8*)(hi + i) = h8;
    if (lo) *(bf16x8*)(lo + i) = l8;
}

// ---------------------------------------------------------------- k_proj2: x @ {wq,wk,wv}^T (pre-split weights)
__global__ __launch_bounds__(256) void k_proj2(
    const float* __restrict__ x,
    const bf16* __restrict__ wqh, const bf16* __restrict__ wql,
    const bf16* __restrict__ wkh, const bf16* __restrict__ wkl,
    const bf16* __restrict__ wvh,
    bf16* __restrict__ Qh, bf16* __restrict__ Ql,
    bf16* __restrict__ Kh, bf16* __restrict__ Kl,
    bf16* __restrict__ Vt)
{
    const int rb = blockIdx.x;
    const int cb = blockIdx.y;
    const int wid = threadIdx.x >> 6;
    const int l   = threadIdx.x & 63;
    const int lg = l >> 4, lr = l & 15;
    const int row = rb * 64 + wid * 16 + lr;

    f32x4 aq[4], ak[4], av[4];
#pragma unroll
    for (int c = 0; c < 4; ++c) {
        aq[c] = f32x4{0.f,0.f,0.f,0.f}; ak[c] = f32x4{0.f,0.f,0.f,0.f}; av[c] = f32x4{0.f,0.f,0.f,0.f};
    }

    for (int ks = 0; ks < 16; ++ks) {
        const int e0 = ks * 32 + lg * 8;
        f32x8 xv = *(const f32x8*)(x + (size_t)row * EE + e0);
        bf16x8 xh, xl;
#pragma unroll
        for (int i = 0; i < 8; ++i) {
            bf16 h = (bf16)xv[i];
            xh[i] = h;
            xl[i] = (bf16)(xv[i] - (float)h);
        }
#pragma unroll
        for (int c = 0; c < 4; ++c) {
            const int f = cb * 64 + c * 16 + lr;
            const size_t wo = (size_t)f * EE + e0;
            bf16x8 qh = *(const bf16x8*)(wqh + wo);
            bf16x8 ql = *(const bf16x8*)(wql + wo);
            bf16x8 kh = *(const bf16x8*)(wkh + wo);
            bf16x8 kl = *(const bf16x8*)(wkl + wo);
            bf16x8 vh = *(const bf16x8*)(wvh + wo);
            aq[c] = mfma16(xh, qh, aq[c]); aq[c] = mfma16(xh, ql, aq[c]); aq[c] = mfma16(xl, qh, aq[c]);
            ak[c] = mfma16(xh, kh, ak[c]); ak[c] = mfma16(xh, kl, ak[c]); ak[c] = mfma16(xl, kh, ak[c]);
            av[c] = mfma16(xh, vh, av[c]);
        }
    }

#pragma unroll
    for (int c = 0; c < 4; ++c)
#pragma unroll
        for (int r = 0; r < 4; ++r) {
            const int orow = rb * 64 + wid * 16 + lg * 4 + r;
            const int b = orow >> 10, t = orow & 1023;
            const int f = cb * 64 + c * 16 + lr;
            const int h = f >> 6, d = f & 63;
            const size_t idx = ((size_t)(b * HH + h) * TT + t) * HDD + d;
            float vq = aq[c][r];
            bf16 qhi = (bf16)vq; Qh[idx] = qhi; Ql[idx] = (bf16)(vq - (float)qhi);
            float vk = ak[c][r];
            bf16 khi = (bf16)vk; Kh[idx] = khi; Kl[idx] = (bf16)(vk - (float)khi);
            Vt[(((size_t)(b * HH + h) * HDD + d) * TT) + t] = (bf16)av[c][r];
        }
}

// ---------------------------------------------------------------- k_ubias2: u -> bf16 ubias chunks inside attn region
// chunk(b,h,ib) = (bf16*)(A + ((bh*1024 + ib*16) * 1024)); layout [i&15][j]
__global__ __launch_bounds__(256) void k_ubias2(
    const float* __restrict__ u, const unsigned char* __restrict__ umask,
    const float* __restrict__ wu, const float* __restrict__ bu,
    float* __restrict__ A)
{
    __shared__ __align__(16) unsigned char msk[64][64];   // [j-rel][i-rel]
    const int b  = blockIdx.z;
    const int i0 = blockIdx.y * 64;
    const int j0 = blockIdx.x * 64;
    const int t  = threadIdx.x;

    {
        const int jj  = t >> 2;
        const int seg = (t & 3) * 16;
        *(uint4*)(&msk[jj][seg]) =
            *(const uint4*)(umask + ((size_t)b * TT + (j0 + jj)) * TT + i0 + seg);
    }
    float wuv[HH][CUc], buv[HH];
#pragma unroll
    for (int h = 0; h < HH; ++h) {
        buv[h] = bu[h];
#pragma unroll
        for (int c = 0; c < CUc; ++c) wuv[h][c] = wu[h * CUc + c];
    }
    __syncthreads();

    const int j = j0 + (t & 63);
    for (int ii = (t >> 6); ii < 64; ii += 4) {
        const int i = i0 + ii;
        float uv[CUc];
#pragma unroll
        for (int c = 0; c < CUc; ++c)
            uv[c] = u[(((size_t)b * CUc + c) * TT + i) * TT + j];
        const bool mk = msk[t & 63][ii] != 0;
#pragma unroll
        for (int h = 0; h < HH; ++h) {
            float v = buv[h];
#pragma unroll
            for (int c = 0; c < CUc; ++c) v += uv[c] * wuv[h][c];
            if (mk) v = -INFINITY;
            bf16* ub = (bf16*)(A + ((size_t)(b * HH + h) * TT + (i & ~15)) * TT);
            ub[(i & 15) * TT + j] = (bf16)v;
        }
    }
}

// ---------------------------------------------------------------- k_fused2: one (b,h,i16) block; 1 barrier
// Deferred-rescale softmax: per-wave local (m,s); global fix-up after the single barrier.
__global__ __launch_bounds__(512, 2) void k_fused2(
    const bf16* __restrict__ Qh, const bf16* __restrict__ Ql,
    const bf16* __restrict__ Kh, const bf16* __restrict__ Kl,
    const bf16* __restrict__ Vt,
    float* __restrict__ A, bf16* __restrict__ ctx)
{
    const int bh = blockIdx.x & 63;         // same (b,h) -> same XCD (stride 64 % 8 == 0)
    const int ib = blockIdx.x >> 6;
    const int b  = bh >> 3, h = bh & 7;
    const int i0 = ib * 16;
    const int w  = threadIdx.x >> 6;        // 8 waves, each owns j-slice [w*128, w*128+128)
    const int l  = threadIdx.x & 63;
    const int lg = l >> 4, lr = l & 15;
    const int jw = w * 128;

    __shared__ __align__(16) bf16  P[16][1032];          // 33 KB (intra-wave reshuffle only)
    __shared__ __align__(16) float ctxred[8][16][64];    // 32 KB
    __shared__ float mred[8][16], sred[8][16];

    // ---- UB prefetch (32 independent 2B loads, all in flight)
    const bf16* ubc = (const bf16*)(A + ((size_t)bh * TT + i0) * TT);
    bf16 ubv[8][4];
#pragma unroll
    for (int jt = 0; jt < 8; ++jt)
#pragma unroll
        for (int r = 0; r < 4; ++r)
            ubv[jt][r] = ubc[(size_t)(lg * 4 + r) * TT + jw + jt * 16 + lr];

    // ---- Q fragments
    const bf16* qph = Qh + ((size_t)bh * TT + i0) * HDD;
    const bf16* qpl = Ql + ((size_t)bh * TT + i0) * HDD;
    bf16x8 qh0 = *(const bf16x8*)(qph + lr * HDD + lg * 8);
    bf16x8 qh1 = *(const bf16x8*)(qph + lr * HDD + 32 + lg * 8);
    bf16x8 ql0 = *(const bf16x8*)(qpl + lr * HDD + lg * 8);
    bf16x8 ql1 = *(const bf16x8*)(qpl + lr * HDD + 32 + lg * 8);

    const bf16* kph = Kh + (size_t)bh * TT * HDD;
    const bf16* kpl = Kl + (size_t)bh * TT * HDD;

    // ---- QK^T + ubias -> s (regs). lane: rows lg*4+r, cols jw+jt*16+lr
    f32x4 s[8];
#pragma unroll
    for (int jt = 0; jt < 8; ++jt) {
        const int j = jw + jt * 16;
        bf16x8 kh0 = *(const bf16x8*)(kph + (size_t)(j + lr) * HDD + lg * 8);
        bf16x8 kh1 = *(const bf16x8*)(kph + (size_t)(j + lr) * HDD + 32 + lg * 8);
        bf16x8 kl0 = *(const bf16x8*)(kpl + (size_t)(j + lr) * HDD + lg * 8);
        bf16x8 kl1 = *(const bf16x8*)(kpl + (size_t)(j + lr) * HDD + 32 + lg * 8);
        f32x4 acc = f32x4{0.f,0.f,0.f,0.f};
        acc = mfma16(qh0, kh0, acc); acc = mfma16(qh1, kh1, acc);
        acc = mfma16(qh0, kl0, acc); acc = mfma16(qh1, kl1, acc);
        acc = mfma16(ql0, kh0, acc); acc = mfma16(ql1, kh1, acc);
#pragma unroll
        for (int r = 0; r < 4; ++r)
            acc[r] = acc[r] * 8.0f + (float)ubv[jt][r];
        s[jt] = acc;
    }

    // ---- wave-local row max (over this wave's 128 cols)
    float m[4];
#pragma unroll
    for (int r = 0; r < 4; ++r) {
        float mm = s[0][r];
#pragma unroll
        for (int jt = 1; jt < 8; ++jt) mm = fmaxf(mm, s[jt][r]);
        m[r] = mm;
    }
#pragma unroll
    for (int off = 1; off < 16; off <<= 1)
#pragma unroll
        for (int r = 0; r < 4; ++r) m[r] = fmaxf(m[r], __shfl_xor(m[r], off));

    // ---- exp vs LOCAL max; P -> LDS (own tile); local row sums
    float mexp[4];
#pragma unroll
    for (int r = 0; r < 4; ++r) mexp[r] = (m[r] == -INFINITY) ? 0.f : m[r];
    float sum[4] = {0.f, 0.f, 0.f, 0.f};
#pragma unroll
    for (int jt = 0; jt < 8; ++jt)
#pragma unroll
        for (int r = 0; r < 4; ++r) {
            float p = __expf(s[jt][r] - mexp[r]);
            s[jt][r] = p;
            sum[r] += p;
            P[lg * 4 + r][jw + jt * 16 + lr] = (bf16)p;
        }
#pragma unroll
    for (int off = 1; off < 16; off <<= 1)
#pragma unroll
        for (int r = 0; r < 4; ++r) sum[r] += __shfl_xor(sum[r], off);
    if (lr == 0)
#pragma unroll
        for (int r = 0; r < 4; ++r) { mred[w][lg * 4 + r] = m[r]; sred[w][lg * 4 + r] = sum[r]; }

    // ---- PV on own k-slice (P reads are this wave's own writes; no barrier needed)
    const bf16* vp = Vt + (size_t)bh * HDD * TT;
    f32x4 cacc[4];
#pragma unroll
    for (int dt = 0; dt < 4; ++dt) cacc[dt] = f32x4{0.f,0.f,0.f,0.f};
#pragma unroll
    for (int ks = 0; ks < 4; ++ks) {
        const int k0 = jw + ks * 32;
        bf16x8 a = *(const bf16x8*)(&P[lr][k0 + lg * 8]);
#pragma unroll
        for (int dt = 0; dt < 4; ++dt) {
            bf16x8 bv = *(const bf16x8*)(vp + (size_t)(dt * 16 + lr) * TT + k0 + lg * 8);
            cacc[dt] = mfma16(a, bv, cacc[dt]);
        }
    }
#pragma unroll
    for (int dt = 0; dt < 4; ++dt)
#pragma unroll
        for (int r = 0; r < 4; ++r)
            ctxred[w][lg * 4 + r][dt * 16 + lr] = cacc[dt][r];

    __syncthreads();                                     // the ONE barrier

    // ---- global (M,S) per row; attn = p_local * exp(m_w - M) / S
    float fac[4];
#pragma unroll
    for (int r = 0; r < 4; ++r) {
        const int row = lg * 4 + r;
        float M = mred[0][row];
#pragma unroll
        for (int wv = 1; wv < 8; ++wv) M = fmaxf(M, mred[wv][row]);
        float S = 0.f;
#pragma unroll
        for (int wv = 0; wv < 8; ++wv) S += sred[wv][row] * __expf(mred[wv][row] - M);
        fac[r] = __expf(m[r] - M) / S;
    }
    float* Ar = A + ((size_t)bh * TT + i0) * TT;
#pragma unroll
    for (int jt = 0; jt < 8; ++jt)
#pragma unroll
        for (int r = 0; r < 4; ++r)
            Ar[(size_t)(lg * 4 + r) * TT + jw + jt * 16 + lr] = s[jt][r] * fac[r];

    // ---- ctx combine: Σ_w ctx_w * exp(m_w - M) / S
    for (int o = threadIdx.x; o < 16 * 64; o += 512) {
        const int row = o >> 6, d = o & 63;
        float M = mred[0][row];
#pragma unroll
        for (int wv = 1; wv < 8; ++wv) M = fmaxf(M, mred[wv][row]);
        float S = 0.f, sm = 0.f;
#pragma unroll
        for (int wv = 0; wv < 8; ++wv) {
            const float e = __expf(mred[wv][row] - M);
            S  += sred[wv][row] * e;
            sm += ctxred[wv][row][d] * e;
        }
        ctx[((size_t)b * TT + i0 + row) * EE + h * HDD + d] = (bf16)(sm / S);
    }
}

// ---------------------------------------------------------------- k_out2: out = ctx @ wo^T + bo
__global__ __launch_bounds__(256) void k_out2(
    const bf16* __restrict__ ctx, const bf16* __restrict__ woh,
    const float* __restrict__ bo, float* __restrict__ out)
{
    const int rb = blockIdx.x;
    const int cb = blockIdx.y;
    const int wid = threadIdx.x >> 6;
    const int l = threadIdx.x & 63;
    const int lg = l >> 4, lr = l & 15;
    const int row = rb * 64 + wid * 16 + lr;

    f32x4 acc[4];
#pragma unroll
    for (int c = 0; c < 4; ++c) acc[c] = f32x4{0.f,0.f,0.f,0.f};

    for (int ks = 0; ks < 16; ++ks) {
        const int e0 = ks * 32 + lg * 8;
        bf16x8 af = *(const bf16x8*)(ctx + (size_t)row * EE + e0);
#pragma unroll
        for (int c = 0; c < 4; ++c) {
            const int f = cb * 64 + c * 16 + lr;
            bf16x8 wf = *(const bf16x8*)(woh + (size_t)f * EE + e0);
            acc[c] = mfma16(af, wf, acc[c]);
        }
    }
#pragma unroll
    for (int c = 0; c < 4; ++c) {
        const int f = cb * 64 + c * 16 + lr;
        const float bov = bo[f];
#pragma unroll
        for (int r = 0; r < 4; ++r) {
            const int orow = rb * 64 + wid * 16 + lg * 4 + r;
            out[(size_t)orow * EE + f] = acc[c][r] + bov;
        }
    }
}

// ----------------------------------------------------------------
extern "C" void kernel_launch(void* const* d_in, const int* in_sizes, int n_in,
                              void* d_out, int out_size, void* d_ws, size_t ws_size,
                              hipStream_t stream)
{
    (void)in_sizes; (void)n_in; (void)out_size; (void)ws_size;
    const float* x  = (const float*)d_in[0];
    const float* u  = (const float*)d_in[1];
    const unsigned char* umask = (const unsigned char*)d_in[2];
    const float* wq = (const float*)d_in[3];
    const float* wk = (const float*)d_in[4];
    const float* wv = (const float*)d_in[5];
    const float* wo = (const float*)d_in[6];
    const float* bo = (const float*)d_in[7];
    const float* wu = (const float*)d_in[8];
    const float* bu = (const float*)d_in[9];

    float* out = (float*)d_out;
    float* A   = out + (size_t)BSZ * TT * EE;       // attn region of d_out

    const size_t qs = (size_t)BSZ * HH * TT * HDD;  // 4,194,304
    const size_t wsz = (size_t)EE * EE;             // 262,144
    bf16* Qh  = (bf16*)d_ws;
    bf16* Ql  = Qh + qs;
    bf16* Kh  = Ql + qs;
    bf16* Kl  = Kh + qs;
    bf16* Vt  = Kl + qs;
    bf16* ctx = Vt + qs;
    bf16* wqh = ctx + qs;
    bf16* wql = wqh + wsz;
    bf16* wkh = wql + wsz;
    bf16* wkl = wkh + wsz;
    bf16* wvh = wkl + wsz;
    bf16* woh = wvh + wsz;                          // total ws: ~51.5 MB

    k_split<<<128, 256, 0, stream>>>(wq, wqh, wql, (int)wsz);
    k_split<<<128, 256, 0, stream>>>(wk, wkh, wkl, (int)wsz);
    k_split<<<128, 256, 0, stream>>>(wv, wvh, nullptr, (int)wsz);
    k_split<<<128, 256, 0, stream>>>(wo, woh, nullptr, (int)wsz);

    k_ubias2<<<dim3(16, 16, 8), 256, 0, stream>>>(u, umask, wu, bu, A);
    k_proj2 <<<dim3(128, 8), 256, 0, stream>>>(x, wqh, wql, wkh, wkl, wvh, Qh, Ql, Kh, Kl, Vt);
    k_fused2<<<4096, 512, 0, stream>>>(Qh, Ql, Kh, Kl, Vt, A, ctx);
    k_out2  <<<dim3(128, 8), 256, 0, stream>>>(ctx, woh, bo, out);
}